// Round 10
// baseline (124.393 us; speedup 1.0000x reference)
//
#include <hip/hip_runtime.h>
#include <stdint.h>

#define IN_F 4096
#define OUT_F 11008
#define M_ROWS 256
#define RANK 16
#define NWORDS 256           // packed words per output row

#define BM 32                // M-rows per block (A-slice in LDS)
#define BN 256               // N-cols per block (8 waves x 32)
#define KSPLIT 4
#define K_PER 1024           // K per block
#define KITER 16             // 64 k per iteration

typedef unsigned short u16;
typedef __attribute__((ext_vector_type(8))) short short8;
typedef __attribute__((ext_vector_type(4))) float floatx4;

__device__ __forceinline__ u16 f32_to_bf16_rne(float f) {
    uint32_t u = __builtin_bit_cast(uint32_t, f);
    uint32_t r = (u + 0x7FFFu + ((u >> 16) & 1u)) >> 16;
    return (u16)r;
}

// ---------------- prep: rowsum, lora_xA, x->bf16 (float4-vectorized) --------
__global__ __launch_bounds__(256) void prep_kernel(
    const float* __restrict__ x, const float* __restrict__ lora_A,
    u16* __restrict__ xb, float* __restrict__ srow, float* __restrict__ lxa)
{
    const int m = blockIdx.x;
    const int tid = threadIdx.x;
    const float4* xrow4 = (const float4*)(x + (size_t)m * IN_F);
    const float4* la4 = (const float4*)lora_A;
    float ssum = 0.f;
    float acc[RANK];
#pragma unroll
    for (int r = 0; r < RANK; ++r) acc[r] = 0.f;
#pragma unroll
    for (int t = 0; t < IN_F / (256 * 4); ++t) {
        int i4 = t * 256 + tid;
        float4 v = xrow4[i4];
        ssum += v.x + v.y + v.z + v.w;
        union { u16 h[4]; uint2 u2; } pk;
        pk.h[0] = f32_to_bf16_rne(v.x);
        pk.h[1] = f32_to_bf16_rne(v.y);
        pk.h[2] = f32_to_bf16_rne(v.z);
        pk.h[3] = f32_to_bf16_rne(v.w);
        *(uint2*)&xb[(size_t)m * IN_F + i4 * 4] = pk.u2;
#pragma unroll
        for (int r = 0; r < RANK; ++r) {
            float4 a = la4[r * (IN_F / 4) + i4];
            acc[r] = fmaf(v.x, a.x, fmaf(v.y, a.y, fmaf(v.z, a.z, fmaf(v.w, a.w, acc[r]))));
        }
    }
#pragma unroll
    for (int off = 32; off > 0; off >>= 1) {
        ssum += __shfl_down(ssum, off, 64);
#pragma unroll
        for (int r = 0; r < RANK; ++r) acc[r] += __shfl_down(acc[r], off, 64);
    }
    __shared__ float red[4][RANK + 1];
    int wv = tid >> 6, ln = tid & 63;
    if (ln == 0) {
        red[wv][0] = ssum;
#pragma unroll
        for (int r = 0; r < RANK; ++r) red[wv][1 + r] = acc[r];
    }
    __syncthreads();
    if (tid == 0) srow[m] = red[0][0] + red[1][0] + red[2][0] + red[3][0];
    if (tid < RANK)
        lxa[m * RANK + tid] = red[0][1 + tid] + red[1][1 + tid] + red[2][1 + tid] + red[3][1 + tid];
}

// ---------------- init: out = bias + mu*rowsum + 2*(lxa . B^T) --------------
__global__ __launch_bounds__(256) void init_kernel(
    const float* __restrict__ mu,
    const float* __restrict__ bias, const float* __restrict__ lora_B,
    const float* __restrict__ srow, const float* __restrict__ lxa,
    float* __restrict__ out)
{
    const int tid = threadIdx.x;
    const int o = blockIdx.x * 256 + tid;
    const int m0 = blockIdx.y * 32;
    float bi = bias[o];
    float muv = mu[o];
    float Br[RANK];
    const float4* b4 = (const float4*)(lora_B + (size_t)o * RANK);
#pragma unroll
    for (int r4 = 0; r4 < RANK / 4; ++r4) {
        float4 v = b4[r4];
        Br[r4 * 4 + 0] = v.x; Br[r4 * 4 + 1] = v.y;
        Br[r4 * 4 + 2] = v.z; Br[r4 * 4 + 3] = v.w;
    }
    __shared__ float ss[32];
    __shared__ float slx[32][RANK];
    if (tid < 32) ss[tid] = srow[m0 + tid];
    for (int t = tid; t < 32 * RANK; t += 256)
        slx[t >> 4][t & 15] = lxa[(m0 + (t >> 4)) * RANK + (t & 15)];
    __syncthreads();
#pragma unroll 4
    for (int mm = 0; mm < 32; ++mm) {
        float dot = 0.f;
#pragma unroll
        for (int r = 0; r < RANK; ++r) dot = fmaf(slx[mm][r], Br[r], dot);
        out[(size_t)(m0 + mm) * OUT_F + o] = bi + muv * ss[mm] + 2.0f * dot;
    }
}

// --- barrier-free streaming GEMM ---
// Block: A-slice [32 rows x 1024 k] staged ONCE in LDS (XOR-swizzled via
// pre-swizzled gload_lds source); 2KB byte->4xbf16 LUT replaces VALU decode.
// 8 waves each own 32 N-cols; K-loop has NO barriers, read-only LDS/global,
// fully unrolled -> compiler pipelines with exact waitcnts.
// Epilogue: atomicAdd(alpha*acc) onto init-kernel output (split-K=4).
__global__ __launch_bounds__(512, 4) void gemm_kernel(
    const u16* __restrict__ xb, const uint32_t* __restrict__ Tp,
    const float* __restrict__ alpha, float* __restrict__ out)
{
    __shared__ __align__(16) u16 ldsA[BM * K_PER];   // 64 KB
    __shared__ __align__(8) uint2 lut[256];          // 2 KB

    const int tid = threadIdx.x;
    const int lane = tid & 63;
    const int wave = tid >> 6;
    const int nb = blockIdx.x * BN;
    const int mb = blockIdx.y * BM;
    const int z = blockIdx.z;

    // ---- build decode LUT: byte -> 4 bf16 (code c -> c-1) ----
    if (tid < 256) {
        const u16 map[4] = {0xBF80u, 0x0000u, 0x3F80u, 0x3F80u};
        uint32_t b = tid;
        uint2 e;
        e.x = (uint32_t)map[b & 3] | ((uint32_t)map[(b >> 2) & 3] << 16);
        e.y = (uint32_t)map[(b >> 4) & 3] | ((uint32_t)map[(b >> 6) & 3] << 16);
        lut[tid] = e;
    }

    // ---- stage A-slice once: 4096 x 16B chunks, 8 per thread ----
    // LDS[row][c] = global chunk (c ^ (row&7)) of row  (involution swizzle);
    // dest = wave-uniform base + lane*16 exactly (HW rule m104/m108).
    {
        const u16* base = xb + (size_t)mb * IN_F + z * K_PER;
#pragma unroll
        for (int i = 0; i < 8; ++i) {
            int q = i * 512 + tid;
            int row = q >> 7;            // 128 chunks per row
            int c = q & 127;
            int sc = c ^ (row & 7);
            __builtin_amdgcn_global_load_lds(
                (const __attribute__((address_space(1))) void*)(base + (size_t)row * IN_F + sc * 8),
                (__attribute__((address_space(3))) void*)(&ldsA[q * 8]),
                16, 0, 0);
        }
    }
    __syncthreads();   // compiler emits full vmcnt drain before barrier

    // ---- per-wave addressing ----
    const int bshift = ((lane >> 4) & 1) * 16;
    // wave owns cols nb + wave*32 .. +31 (two 16-col fragments nt=0,1)
    const uint32_t* bp0 = Tp + (size_t)(nb + wave * 32 + (lane & 15)) * NWORDS
                            + z * (K_PER / 16) + (lane >> 5);
    const uint32_t* bp1 = bp0 + 16 * NWORDS;

    // A-frag offsets (u16 units); XOR stays within low 3 chunk bits
    int aoff[2][2];
#pragma unroll
    for (int mt = 0; mt < 2; ++mt)
#pragma unroll
        for (int kk = 0; kk < 2; ++kk) {
            int row = mt * 16 + (lane & 15);
            int sc = kk * 4 + (lane >> 4);
            aoff[mt][kk] = row * K_PER + ((sc ^ (row & 7)) * 8);
        }

    floatx4 acc[2][2] = {};

    // ---- K-loop: no barriers, read-only LDS + global ----
#pragma unroll
    for (int j = 0; j < KITER; ++j) {
#pragma unroll
        for (int kk = 0; kk < 2; ++kk) {
            uint32_t w0 = bp0[j * 4 + kk * 2];
            uint32_t w1 = bp1[j * 4 + kk * 2];
            uint32_t h0 = (w0 >> bshift) & 0xFFFFu;
            uint32_t h1 = (w1 >> bshift) & 0xFFFFu;
            uint2 a0 = lut[h0 & 0xFFu], b0 = lut[h0 >> 8];
            uint2 a1 = lut[h1 & 0xFFu], b1 = lut[h1 >> 8];
            union { uint32_t u[4]; short8 s; } f0, f1;
            f0.u[0] = a0.x; f0.u[1] = a0.y; f0.u[2] = b0.x; f0.u[3] = b0.y;
            f1.u[0] = a1.x; f1.u[1] = a1.y; f1.u[2] = b1.x; f1.u[3] = b1.y;
#pragma unroll
            for (int mt = 0; mt < 2; ++mt) {
                const short8 af = *(const short8*)&ldsA[aoff[mt][kk] + j * 64];
                acc[mt][0] = __builtin_amdgcn_mfma_f32_16x16x32_bf16(af, f0.s, acc[mt][0], 0, 0, 0);
                acc[mt][1] = __builtin_amdgcn_mfma_f32_16x16x32_bf16(af, f1.s, acc[mt][1], 0, 0, 0);
            }
        }
    }

    // ---- epilogue: atomic add alpha * acc onto init values ----
    const int o0 = nb + wave * 32 + (lane & 15);
    const float al0 = alpha[o0];
    const float al1 = alpha[o0 + 16];
#pragma unroll
    for (int mt = 0; mt < 2; ++mt) {
#pragma unroll
        for (int rg = 0; rg < 4; ++rg) {
            int m = mb + mt * 16 + ((lane >> 4) & 3) * 4 + rg;
            atomicAdd(&out[(size_t)m * OUT_F + o0], al0 * acc[mt][0][rg]);
            atomicAdd(&out[(size_t)m * OUT_F + o0 + 16], al1 * acc[mt][1][rg]);
        }
    }
}

extern "C" void kernel_launch(void* const* d_in, const int* in_sizes, int n_in,
                              void* d_out, int out_size, void* d_ws, size_t ws_size,
                              hipStream_t stream)
{
    const float* x = (const float*)d_in[0];
    const uint32_t* Tp = (const uint32_t*)d_in[1];
    const float* alpha = (const float*)d_in[2];
    const float* mu = (const float*)d_in[3];
    const float* bias = (const float*)d_in[4];
    const float* lora_A = (const float*)d_in[5];
    const float* lora_B = (const float*)d_in[6];
    float* out = (float*)d_out;

    u16* xb = (u16*)d_ws;
    float* srow = (float*)((char*)d_ws + (size_t)M_ROWS * IN_F * 2);
    float* lxa = (float*)((char*)d_ws + (size_t)M_ROWS * IN_F * 2 + 4096);

    prep_kernel<<<dim3(M_ROWS), dim3(256), 0, stream>>>(x, lora_A, xb, srow, lxa);
    init_kernel<<<dim3(OUT_F / 256, M_ROWS / 32), dim3(256), 0, stream>>>(
        mu, bias, lora_B, srow, lxa, out);
    gemm_kernel<<<dim3(OUT_F / BN, M_ROWS / BM, KSPLIT), dim3(512), 0, stream>>>(
        xb, Tp, alpha, out);
}

// Round 11
// 124.187 us; speedup vs baseline: 1.0017x; 1.0017x over previous
//
#include <hip/hip_runtime.h>
#include <stdint.h>

#define IN_F 4096
#define OUT_F 11008
#define M_ROWS 256
#define RANK 16
#define NWORDS 256           // packed words per T row

#define KSPLIT 4
#define K_PER 1024
#define NIT 32               // K_PER / 32

typedef unsigned short u16;
typedef __attribute__((ext_vector_type(8))) short short8;
typedef __attribute__((ext_vector_type(4))) float floatx4;

__device__ __forceinline__ u16 f32_to_bf16_rne(float f) {
    uint32_t u = __builtin_bit_cast(uint32_t, f);
    uint32_t r = (u + 0x7FFFu + ((u >> 16) & 1u)) >> 16;
    return (u16)r;
}

// ---------------- prep: rowsum, lora_xA, x->bf16 ----------------
__global__ __launch_bounds__(256) void prep_kernel(
    const float* __restrict__ x, const float* __restrict__ lora_A,
    u16* __restrict__ xb, float* __restrict__ srow, float* __restrict__ lxa)
{
    const int m = blockIdx.x;
    const int tid = threadIdx.x;
    const float4* xrow4 = (const float4*)(x + (size_t)m * IN_F);
    const float4* la4 = (const float4*)lora_A;
    float ssum = 0.f;
    float acc[RANK];
#pragma unroll
    for (int r = 0; r < RANK; ++r) acc[r] = 0.f;
#pragma unroll
    for (int t = 0; t < IN_F / (256 * 4); ++t) {
        int i4 = t * 256 + tid;
        float4 v = xrow4[i4];
        ssum += v.x + v.y + v.z + v.w;
        union { u16 h[4]; uint2 u2; } pk;
        pk.h[0] = f32_to_bf16_rne(v.x);
        pk.h[1] = f32_to_bf16_rne(v.y);
        pk.h[2] = f32_to_bf16_rne(v.z);
        pk.h[3] = f32_to_bf16_rne(v.w);
        *(uint2*)&xb[(size_t)m * IN_F + i4 * 4] = pk.u2;
#pragma unroll
        for (int r = 0; r < RANK; ++r) {
            float4 a = la4[r * (IN_F / 4) + i4];
            acc[r] = fmaf(v.x, a.x, fmaf(v.y, a.y, fmaf(v.z, a.z, fmaf(v.w, a.w, acc[r]))));
        }
    }
#pragma unroll
    for (int off = 32; off > 0; off >>= 1) {
        ssum += __shfl_down(ssum, off, 64);
#pragma unroll
        for (int r = 0; r < RANK; ++r) acc[r] += __shfl_down(acc[r], off, 64);
    }
    __shared__ float red[4][RANK + 1];
    int wv = tid >> 6, ln = tid & 63;
    if (ln == 0) {
        red[wv][0] = ssum;
#pragma unroll
        for (int r = 0; r < RANK; ++r) red[wv][1 + r] = acc[r];
    }
    __syncthreads();
    if (tid == 0) srow[m] = red[0][0] + red[1][0] + red[2][0] + red[3][0];
    if (tid < RANK)
        lxa[m * RANK + tid] = red[0][1 + tid] + red[1][1 + tid] + red[2][1 + tid] + red[3][1 + tid];
}

// ------- pack: Tw2[wp][col] = (Tp[col][2wp], Tp[col][2wp+1]), LDS-tiled -----
__global__ __launch_bounds__(256) void pack_kernel(
    const uint32_t* __restrict__ Tp, uint2* __restrict__ Tw2)
{
    __shared__ uint32_t s[64][NWORDS + 1];   // +1 pad: 2-way banks on read
    const int tid = threadIdx.x;
    const int col0 = blockIdx.x * 64;
#pragma unroll 8
    for (int i = 0; i < 64; ++i) {
        int idx = i * 256 + tid;             // coalesced read: 1KB per col
        s[idx >> 8][idx & 255] = Tp[(size_t)(col0 + (idx >> 8)) * NWORDS + (idx & 255)];
    }
    __syncthreads();
    const int c = tid & 63;
#pragma unroll 8
    for (int p = 0; p < 32; ++p) {
        int wp = p * 4 + (tid >> 6);
        uint2 v; v.x = s[c][2 * wp]; v.y = s[c][2 * wp + 1];
        Tw2[(size_t)wp * OUT_F + col0 + c] = v;   // coalesced write
    }
}

// ---------------- init: out = bias + mu*rowsum + 2*(lxa . B^T) --------------
__global__ __launch_bounds__(256) void init_kernel(
    const float* __restrict__ mu,
    const float* __restrict__ bias, const float* __restrict__ lora_B,
    const float* __restrict__ srow, const float* __restrict__ lxa,
    float* __restrict__ out)
{
    const int tid = threadIdx.x;
    const int o = blockIdx.x * 256 + tid;
    const int m0 = blockIdx.y * 32;
    float bi = bias[o];
    float muv = mu[o];
    float Br[RANK];
    const float4* b4 = (const float4*)(lora_B + (size_t)o * RANK);
#pragma unroll
    for (int r4 = 0; r4 < RANK / 4; ++r4) {
        float4 v = b4[r4];
        Br[r4 * 4 + 0] = v.x; Br[r4 * 4 + 1] = v.y;
        Br[r4 * 4 + 2] = v.z; Br[r4 * 4 + 3] = v.w;
    }
    __shared__ float ss[32];
    __shared__ float slx[32][RANK];
    if (tid < 32) ss[tid] = srow[m0 + tid];
    for (int t = tid; t < 32 * RANK; t += 256)
        slx[t >> 4][t & 15] = lxa[(m0 + (t >> 4)) * RANK + (t & 15)];
    __syncthreads();
#pragma unroll 4
    for (int mm = 0; mm < 32; ++mm) {
        float dot = 0.f;
#pragma unroll
        for (int r = 0; r < RANK; ++r) dot = fmaf(slx[mm][r], Br[r], dot);
        out[(size_t)(m0 + mm) * OUT_F + o] = bi + muv * ss[mm] + 2.0f * dot;
    }
}

// ---------------- ternary decode (VERIFIED R1-R9) ----------------
__device__ __forceinline__ short8 decode8(uint32_t h)
{
    uint32_t selA = (h & 0xFu) | ((h & 0xF0u) << 12);
    selA = (selA | (selA << 6)) & 0x03030303u;
    uint32_t h2 = h >> 8;
    uint32_t selB = (h2 & 0xFu) | ((h2 & 0xF0u) << 12);
    selB = (selB | (selB << 6)) & 0x03030303u;
    uint32_t hiA = __builtin_amdgcn_perm(0u, 0x003F00BFu, selA);
    uint32_t loA = __builtin_amdgcn_perm(0u, 0x00800080u, selA);
    uint32_t hiB = __builtin_amdgcn_perm(0u, 0x003F00BFu, selB);
    uint32_t loB = __builtin_amdgcn_perm(0u, 0x00800080u, selB);
    union { uint32_t u[4]; short8 s; } cvt;
    cvt.u[0] = __builtin_amdgcn_perm(hiA, loA, 0x05010400u);
    cvt.u[1] = __builtin_amdgcn_perm(hiA, loA, 0x07030602u);
    cvt.u[2] = __builtin_amdgcn_perm(hiB, loB, 0x05010400u);
    cvt.u[3] = __builtin_amdgcn_perm(hiB, loB, 0x07030602u);
    return cvt.s;
}

#define WAITV(N) asm volatile("s_waitcnt vmcnt(" #N ")" ::: "memory")
#define SCHED0   __builtin_amdgcn_sched_barrier(0)

struct Frag { short8 af[4]; };
struct BW   { uint2 w[4]; };

// --- 1-wave blocks, wave-private LDS, ZERO barriers in K-loop ---
// Wave-tile 64x64 (mt4 x nt4), BK=32, 4 private LDS bufs (16 KB).
// Per iter j: issue B(j+1)x4, A(j+3)x4; WAITV(12) retires A(j+1)+B(j)
// (FIFO: A(j+1)[j-2], B(j)[j-1], A(j+2)[j-1], B(j+1)[j], A(j+3)[j]);
// compute(j) from regs; rdfrags(j+1). Self-paced: no cross-wave deps.
__global__ __launch_bounds__(64) void gemm_kernel(
    const u16* __restrict__ xb, const uint2* __restrict__ Tw2,
    const float* __restrict__ alpha, float* __restrict__ out)
{
    __shared__ __align__(16) u16 ldsA[4][64 * 32];   // 4 x 4 KB, wave-private

    const int lane = threadIdx.x;
    const int nb = blockIdx.x * 64;
    const int mb = blockIdx.y * 64;
    const int z = blockIdx.z;

    // A-stage sources: 4 gloads/iter; q=gl*64+lane, row=q>>2, chunk c=q&3
    // dest = buf base + q*16B (linear, HW rule m104/m108); row-stride 64B
    // -> frag-read bank multiplicity matches linear b128 (no swizzle needed)
    const u16* asrc[4];
#pragma unroll
    for (int gl = 0; gl < 4; ++gl) {
        int q = gl * 64 + lane;
        asrc[gl] = xb + (size_t)(mb + (q >> 2)) * IN_F + z * K_PER + (q & 3) * 8;
    }
    // B: Tw2[wp][col], wp = z*32 + j; 16-lane-contiguous uint2 loads
    const uint2* bbase = Tw2 + (size_t)(z * NIT) * OUT_F + nb + (lane & 15);
    const int bshift = ((lane >> 4) & 1) * 16;
    const bool hiw = (lane & 32) != 0;

    int aoff[4];
#pragma unroll
    for (int mt = 0; mt < 4; ++mt)
        aoff[mt] = (mt * 16 + (lane & 15)) * 32 + (lane >> 4) * 8;  // u16 units

    floatx4 acc[4][4] = {};

    auto stage = [&](int buf, int j) {
#pragma unroll
        for (int gl = 0; gl < 4; ++gl) {
            __builtin_amdgcn_global_load_lds(
                (const __attribute__((address_space(1))) void*)(asrc[gl] + j * 32),
                (__attribute__((address_space(3))) void*)(&ldsA[buf][gl * 512]),
                16, 0, 0);
        }
    };
    auto loadB = [&](BW& b, int j) {
#pragma unroll
        for (int nt = 0; nt < 4; ++nt)
            b.w[nt] = bbase[(size_t)j * OUT_F + nt * 16];
    };
    auto rdfrags = [&](int buf, Frag& F) {
#pragma unroll
        for (int mt = 0; mt < 4; ++mt)
            F.af[mt] = *(const short8*)&ldsA[buf][aoff[mt]];
    };
    auto compute = [&](Frag& F, BW& b) {
        __builtin_amdgcn_s_setprio(1);
#pragma unroll
        for (int nt = 0; nt < 4; ++nt) {
            uint32_t w = hiw ? b.w[nt].y : b.w[nt].x;
            short8 bf = decode8((w >> bshift) & 0xFFFFu);
#pragma unroll
            for (int mt = 0; mt < 4; ++mt)
                acc[mt][nt] = __builtin_amdgcn_mfma_f32_16x16x32_bf16(
                    F.af[mt], bf, acc[mt][nt], 0, 0, 0);
        }
        __builtin_amdgcn_s_setprio(0);
    };

    Frag fE, fO;
    BW bwE, bwO;

    // prologue: FIFO = A0,A1,B0,A2 (16)
    stage(0, 0); stage(1, 1);
    loadB(bwE, 0);
    stage(2, 2);
    WAITV(8);                 // retire A0,A1
    rdfrags(0, fE); SCHED0;

    // iter 0: FIFO B0,A2,B1,A3 -> WAITV(8) retires B0,A2
    loadB(bwO, 1); stage(3, 3); SCHED0;
    WAITV(8);
    compute(fE, bwE);
    rdfrags(1, fO); SCHED0;

    // steady j = 1..28 (7 x 4 unroll; j = 1+4u+p)
#pragma unroll 1
    for (int u = 0; u < 7; ++u) {
        const int j = 1 + u * 4;
        loadB(bwE, j + 1); stage((j + 3) & 3, j + 3); SCHED0;
        WAITV(12); compute(fO, bwO); rdfrags((j + 1) & 3, fE); SCHED0;
        loadB(bwO, j + 2); stage((j + 4) & 3, j + 4); SCHED0;
        WAITV(12); compute(fE, bwE); rdfrags((j + 2) & 3, fO); SCHED0;
        loadB(bwE, j + 3); stage((j + 5) & 3, j + 5); SCHED0;
        WAITV(12); compute(fO, bwO); rdfrags((j + 3) & 3, fE); SCHED0;
        loadB(bwO, j + 4); stage((j + 6) & 3, j + 6); SCHED0;
        WAITV(12); compute(fE, bwE); rdfrags((j + 4) & 3, fO); SCHED0;
    }
    // j = 29 (odd): FIFO A30,B29,A31,B30 -> WAITV(8) retires A30,B29
    loadB(bwE, 30); SCHED0;
    WAITV(8); compute(fO, bwO); rdfrags(30 & 3, fE); SCHED0;
    // j = 30: FIFO A31,B30,B31 -> WAITV(4) retires A31,B30
    loadB(bwO, 31); SCHED0;
    WAITV(4); compute(fE, bwE); rdfrags(31 & 3, fO); SCHED0;
    // j = 31
    WAITV(0); compute(fO, bwO);

    // ---- epilogue: atomic add alpha * acc onto init base ----
    const int o0 = nb + (lane & 15);
    const int r0 = mb + ((lane >> 4) & 3) * 4;
    float al[4];
#pragma unroll
    for (int nt = 0; nt < 4; ++nt) al[nt] = alpha[o0 + nt * 16];
#pragma unroll
    for (int mt = 0; mt < 4; ++mt) {
#pragma unroll
        for (int rg = 0; rg < 4; ++rg) {
            int m = r0 + mt * 16 + rg;
#pragma unroll
            for (int nt = 0; nt < 4; ++nt)
                atomicAdd(&out[(size_t)m * OUT_F + o0 + nt * 16],
                          al[nt] * acc[mt][nt][rg]);
        }
    }
}

extern "C" void kernel_launch(void* const* d_in, const int* in_sizes, int n_in,
                              void* d_out, int out_size, void* d_ws, size_t ws_size,
                              hipStream_t stream)
{
    const float* x = (const float*)d_in[0];
    const uint32_t* Tp = (const uint32_t*)d_in[1];
    const float* alpha = (const float*)d_in[2];
    const float* mu = (const float*)d_in[3];
    const float* bias = (const float*)d_in[4];
    const float* lora_A = (const float*)d_in[5];
    const float* lora_B = (const float*)d_in[6];
    float* out = (float*)d_out;

    u16* xb = (u16*)d_ws;                                    // 2 MB
    float* srow = (float*)((char*)d_ws + (size_t)M_ROWS * IN_F * 2);
    float* lxa = (float*)((char*)d_ws + (size_t)M_ROWS * IN_F * 2 + 4096);
    uint2* Tw2 = (uint2*)((char*)d_ws + (4u << 20));         // 11 MB at +4MB

    prep_kernel<<<dim3(M_ROWS), dim3(256), 0, stream>>>(x, lora_A, xb, srow, lxa);
    pack_kernel<<<dim3(OUT_F / 64), dim3(256), 0, stream>>>(Tp, Tw2);
    init_kernel<<<dim3(OUT_F / 256, M_ROWS / 32), dim3(256), 0, stream>>>(
        mu, bias, lora_B, srow, lxa, out);
    gemm_kernel<<<dim3(OUT_F / 64, M_ROWS / 64, KSPLIT), dim3(64), 0, stream>>>(
        xb, Tw2, alpha, out);
}

// Round 12
// 66.044 us; speedup vs baseline: 1.8835x; 1.8804x over previous
//
#include <hip/hip_runtime.h>
#include <stdint.h>

#define IN_F 4096
#define OUT_F 11008
#define M_ROWS 256
#define RANK 16
#define NWORDS 256           // packed words per T row

#define BM 128
#define BN 64
#define BK 64
#define KSPLIT 2
#define K_PER 2048
#define NIT 32               // K_PER / BK

typedef unsigned short u16;
typedef __attribute__((ext_vector_type(8))) short short8;
typedef __attribute__((ext_vector_type(4))) float floatx4;

__device__ __forceinline__ u16 f32_to_bf16_rne(float f) {
    uint32_t u = __builtin_bit_cast(uint32_t, f);
    uint32_t r = (u + 0x7FFFu + ((u >> 16) & 1u)) >> 16;
    return (u16)r;
}

// ---------------- prep: rowsum, lora_xA, x->bf16 (VERIFIED) ----------------
__global__ __launch_bounds__(256) void prep_kernel(
    const float* __restrict__ x, const float* __restrict__ lora_A,
    u16* __restrict__ xb, float* __restrict__ srow, float* __restrict__ lxa)
{
    const int m = blockIdx.x;
    const int tid = threadIdx.x;
    const float4* xrow4 = (const float4*)(x + (size_t)m * IN_F);
    const float4* la4 = (const float4*)lora_A;
    float ssum = 0.f;
    float acc[RANK];
#pragma unroll
    for (int r = 0; r < RANK; ++r) acc[r] = 0.f;
#pragma unroll
    for (int t = 0; t < IN_F / (256 * 4); ++t) {
        int i4 = t * 256 + tid;
        float4 v = xrow4[i4];
        ssum += v.x + v.y + v.z + v.w;
        union { u16 h[4]; uint2 u2; } pk;
        pk.h[0] = f32_to_bf16_rne(v.x);
        pk.h[1] = f32_to_bf16_rne(v.y);
        pk.h[2] = f32_to_bf16_rne(v.z);
        pk.h[3] = f32_to_bf16_rne(v.w);
        *(uint2*)&xb[(size_t)m * IN_F + i4 * 4] = pk.u2;
#pragma unroll
        for (int r = 0; r < RANK; ++r) {
            float4 a = la4[r * (IN_F / 4) + i4];
            acc[r] = fmaf(v.x, a.x, fmaf(v.y, a.y, fmaf(v.z, a.z, fmaf(v.w, a.w, acc[r]))));
        }
    }
#pragma unroll
    for (int off = 32; off > 0; off >>= 1) {
        ssum += __shfl_down(ssum, off, 64);
#pragma unroll
        for (int r = 0; r < RANK; ++r) acc[r] += __shfl_down(acc[r], off, 64);
    }
    __shared__ float red[4][RANK + 1];
    int wv = tid >> 6, ln = tid & 63;
    if (ln == 0) {
        red[wv][0] = ssum;
#pragma unroll
        for (int r = 0; r < RANK; ++r) red[wv][1 + r] = acc[r];
    }
    __syncthreads();
    if (tid == 0) srow[m] = red[0][0] + red[1][0] + red[2][0] + red[3][0];
    if (tid < RANK)
        lxa[m * RANK + tid] = red[0][1 + tid] + red[1][1 + tid] + red[2][1 + tid] + red[3][1 + tid];
}

// ---------------- init: out = bias + mu*rowsum + 2*(lxa . B^T) (VERIFIED) ---
__global__ __launch_bounds__(256) void init_kernel(
    const float* __restrict__ mu,
    const float* __restrict__ bias, const float* __restrict__ lora_B,
    const float* __restrict__ srow, const float* __restrict__ lxa,
    float* __restrict__ out)
{
    const int tid = threadIdx.x;
    const int o = blockIdx.x * 256 + tid;
    const int m0 = blockIdx.y * 32;
    float bi = bias[o];
    float muv = mu[o];
    float Br[RANK];
    const float4* b4 = (const float4*)(lora_B + (size_t)o * RANK);
#pragma unroll
    for (int r4 = 0; r4 < RANK / 4; ++r4) {
        float4 v = b4[r4];
        Br[r4 * 4 + 0] = v.x; Br[r4 * 4 + 1] = v.y;
        Br[r4 * 4 + 2] = v.z; Br[r4 * 4 + 3] = v.w;
    }
    __shared__ float ss[32];
    __shared__ float slx[32][RANK];
    if (tid < 32) ss[tid] = srow[m0 + tid];
    for (int t = tid; t < 32 * RANK; t += 256)
        slx[t >> 4][t & 15] = lxa[(m0 + (t >> 4)) * RANK + (t & 15)];
    __syncthreads();
#pragma unroll 4
    for (int mm = 0; mm < 32; ++mm) {
        float dot = 0.f;
#pragma unroll
        for (int r = 0; r < RANK; ++r) dot = fmaf(slx[mm][r], Br[r], dot);
        out[(size_t)(m0 + mm) * OUT_F + o] = bi + muv * ss[mm] + 2.0f * dot;
    }
}

// ---------------- ternary decode (VERIFIED R1-R11) ----------------
__device__ __forceinline__ short8 decode8(uint32_t h)
{
    uint32_t selA = (h & 0xFu) | ((h & 0xF0u) << 12);
    selA = (selA | (selA << 6)) & 0x03030303u;
    uint32_t h2 = h >> 8;
    uint32_t selB = (h2 & 0xFu) | ((h2 & 0xF0u) << 12);
    selB = (selB | (selB << 6)) & 0x03030303u;
    uint32_t hiA = __builtin_amdgcn_perm(0u, 0x003F00BFu, selA);
    uint32_t loA = __builtin_amdgcn_perm(0u, 0x00800080u, selA);
    uint32_t hiB = __builtin_amdgcn_perm(0u, 0x003F00BFu, selB);
    uint32_t loB = __builtin_amdgcn_perm(0u, 0x00800080u, selB);
    union { uint32_t u[4]; short8 s; } cvt;
    cvt.u[0] = __builtin_amdgcn_perm(hiA, loA, 0x05010400u);
    cvt.u[1] = __builtin_amdgcn_perm(hiA, loA, 0x07030602u);
    cvt.u[2] = __builtin_amdgcn_perm(hiB, loB, 0x05010400u);
    cvt.u[3] = __builtin_amdgcn_perm(hiB, loB, 0x07030602u);
    return cvt.s;
}

#define WAITV5 asm volatile("s_waitcnt vmcnt(5)" ::: "memory")
#define WAITV0 asm volatile("s_waitcnt vmcnt(0)" ::: "memory")
#define BAR    __builtin_amdgcn_s_barrier()
#define SCHED0 __builtin_amdgcn_sched_barrier(0)

struct Frags {
    short8 af[4][2];
    uint32_t bwd[2][2];
};

// --- fused GEMM: 128x64 tile, 4 waves (wave-tile 64x32, mt4/nt2), 3-buf A,
// split-K=2, R6's reg-pipelined iteration. 5 loads/stage -> steady WAITV(5).
// Steady j=0..29 (30 = 5 x unroll-6: buf%3 and fragset parity compile-time).
// decode cost: 4 decode8/wave-iter feeding 16 MFMA (5.75 instr/MFMA, half R6).
__global__ __launch_bounds__(256, 3) void gemm_kernel(
    const u16* __restrict__ xb, const uint32_t* __restrict__ Tp,
    const float* __restrict__ alpha, float* __restrict__ out)
{
    __shared__ __align__(16) u16 ldsA[3][BM * BK];       // 3 x 16 KB
    __shared__ __align__(16) uint32_t ldsB[3][BN * 4];   // 3 x 1 KB

    const int tid = threadIdx.x;
    const int lane = tid & 63;
    const int wave = tid >> 6;
    const int wm = wave >> 1, wn = wave & 1;
    const int mb = blockIdx.y * BM;
    const int nb = blockIdx.x * BN;
    const int z = blockIdx.z;

    const int bshift = ((lane >> 4) & 1) * 16;

    // A-stage: 1024 x 16B chunks; 4 per thread; XOR-swizzled SOURCE, linear
    // dest (= wave base + lane*16 exactly, HW rule m104/m108)
    const u16* asrc[4];
    int adst[4];
#pragma unroll
    for (int i = 0; i < 4; ++i) {
        int q = i * 256 + tid;
        int row = q >> 3;            // 8 chunks per 64-elem row
        int scc = (q & 7) ^ (row & 7);
        asrc[i] = xb + (size_t)(mb + row) * IN_F + z * K_PER + scc * 8;
        adst[i] = q * 8;             // u16 elements
    }
    // B-stage: 64 rows x 16B; all 4 waves duplicate-write (idempotent),
    // keeps per-wave loads/stage uniform at 5
    const uint32_t* bsrc = Tp + (size_t)(nb + lane) * NWORDS + z * (K_PER / 16);
    const int bdst = lane * 4;       // u32 elements

    // fragment offsets (compile-time indexed)
    int aoff[4][2], boff[2][2];
#pragma unroll
    for (int mt = 0; mt < 4; ++mt)
#pragma unroll
        for (int kk = 0; kk < 2; ++kk) {
            int r = wm * 64 + mt * 16 + (lane & 15);
            int sc = kk * 4 + (lane >> 4);
            aoff[mt][kk] = (r * 8 + (sc ^ (r & 7))) * 8;   // u16 units
        }
#pragma unroll
    for (int nt = 0; nt < 2; ++nt)
#pragma unroll
        for (int kk = 0; kk < 2; ++kk) {
            int row = wn * 32 + nt * 16 + (lane & 15);
            boff[nt][kk] = row * 4 + kk * 2 + (lane >> 5);
        }

    floatx4 acc[4][2] = {};

    auto stage = [&](int buf, int jt) {
#pragma unroll
        for (int i = 0; i < 4; ++i) {
            __builtin_amdgcn_global_load_lds(
                (const __attribute__((address_space(1))) void*)(asrc[i] + jt * BK),
                (__attribute__((address_space(3))) void*)(&ldsA[buf][adst[i]]),
                16, 0, 0);
        }
        __builtin_amdgcn_global_load_lds(
            (const __attribute__((address_space(1))) void*)(bsrc + jt * 4),
            (__attribute__((address_space(3))) void*)(&ldsB[buf][bdst]),
            16, 0, 0);
    };

    auto rdfrags = [&](int buf, Frags& F) {
#pragma unroll
        for (int mt = 0; mt < 4; ++mt)
#pragma unroll
            for (int kk = 0; kk < 2; ++kk)
                F.af[mt][kk] = *(const short8*)&ldsA[buf][aoff[mt][kk]];
#pragma unroll
        for (int nt = 0; nt < 2; ++nt)
#pragma unroll
            for (int kk = 0; kk < 2; ++kk)
                F.bwd[nt][kk] = ldsB[buf][boff[nt][kk]];
    };

    auto compute = [&](Frags& F) {
        __builtin_amdgcn_s_setprio(1);
#pragma unroll
        for (int kk = 0; kk < 2; ++kk) {
#pragma unroll
            for (int nt = 0; nt < 2; ++nt) {
                short8 bf = decode8((F.bwd[nt][kk] >> bshift) & 0xFFFFu);
#pragma unroll
                for (int mt = 0; mt < 4; ++mt)
                    acc[mt][nt] = __builtin_amdgcn_mfma_f32_16x16x32_bf16(
                        F.af[mt][kk], bf, acc[mt][nt], 0, 0, 0);
            }
        }
        __builtin_amdgcn_s_setprio(0);
    };

    Frags fA, fB;

    // prologue: fill bufs 0,1 (10 loads); retire buf 0; read frags(0)
    stage(0, 0);
    stage(1, 1);
    WAITV5; BAR;
    rdfrags(0, fA); SCHED0;

    // steady: j = 0..29. Per iter j: stage((j+2)%3, j+2) | compute(j) from
    // regs | WAITV(5) retires S(j+1) | BAR | rdfrags((j+1)%3).
    // Buffer-overwrite safety: buf (j+2)%3 last read at end of iter j-1
    // (as frags j-1... one full barrier between read and overwrite).
#pragma unroll 1
    for (int u = 0; u < 5; ++u) {
        const int j = u * 6;
        stage(2, j + 2); SCHED0; compute(fA); WAITV5; BAR; rdfrags(1, fB); SCHED0;
        stage(0, j + 3); SCHED0; compute(fB); WAITV5; BAR; rdfrags(2, fA); SCHED0;
        stage(1, j + 4); SCHED0; compute(fA); WAITV5; BAR; rdfrags(0, fB); SCHED0;
        stage(2, j + 5); SCHED0; compute(fB); WAITV5; BAR; rdfrags(1, fA); SCHED0;
        stage(0, j + 6); SCHED0; compute(fA); WAITV5; BAR; rdfrags(2, fB); SCHED0;
        stage(1, j + 7); SCHED0; compute(fB); WAITV5; BAR; rdfrags(0, fA); SCHED0;
    }
    // j = 30: queue holds S(31)x5 only -> drain; buf 31%3 = 1
    WAITV0; compute(fA); BAR; rdfrags(1, fB); SCHED0;
    // j = 31
    compute(fB);

    // ---- epilogue: atomic add alpha * acc onto init-kernel base ----
    const int o0 = nb + wn * 32 + (lane & 15);
    const int m0 = mb + wm * 64 + ((lane >> 4) * 4);
    float al[2] = { alpha[o0], alpha[o0 + 16] };
#pragma unroll
    for (int mt = 0; mt < 4; ++mt) {
#pragma unroll
        for (int rg = 0; rg < 4; ++rg) {
            int m = m0 + mt * 16 + rg;
#pragma unroll
            for (int nt = 0; nt < 2; ++nt)
                atomicAdd(&out[(size_t)m * OUT_F + o0 + nt * 16],
                          al[nt] * acc[mt][nt][rg]);
        }
    }
}

extern "C" void kernel_launch(void* const* d_in, const int* in_sizes, int n_in,
                              void* d_out, int out_size, void* d_ws, size_t ws_size,
                              hipStream_t stream)
{
    const float* x = (const float*)d_in[0];
    const uint32_t* Tp = (const uint32_t*)d_in[1];
    const float* alpha = (const float*)d_in[2];
    const float* mu = (const float*)d_in[3];
    const float* bias = (const float*)d_in[4];
    const float* lora_A = (const float*)d_in[5];
    const float* lora_B = (const float*)d_in[6];
    float* out = (float*)d_out;

    u16* xb = (u16*)d_ws;
    float* srow = (float*)((char*)d_ws + (size_t)M_ROWS * IN_F * 2);
    float* lxa = (float*)((char*)d_ws + (size_t)M_ROWS * IN_F * 2 + 4096);

    prep_kernel<<<dim3(M_ROWS), dim3(256), 0, stream>>>(x, lora_A, xb, srow, lxa);
    init_kernel<<<dim3(OUT_F / 256, M_ROWS / 32), dim3(256), 0, stream>>>(
        mu, bias, lora_B, srow, lxa, out);
    gemm_kernel<<<dim3(OUT_F / BN, M_ROWS / BM, KSPLIT), dim3(256), 0, stream>>>(
        xb, Tp, alpha, out);
}